// Round 1
// baseline (3698.570 us; speedup 1.0000x reference)
//
#include <hip/hip_runtime.h>

#define WSZ 8
#define NT 64          // tokens per window
#define CH 192         // channels
#define NH 6           // heads
#define HD 32          // head dim
#define MH 256         // meta hidden
#define BWIN 4096      // windows
#define NMASK 64
#define KSTRIDE 36     // padded LDS row stride for k/v (floats)

// ---------------- kernel 1: relative-position bias table ----------------
// bias_tbl[h][n][m], h<6, n,m<64
__global__ void bias_kernel(const float* __restrict__ mW1, const float* __restrict__ mb1,
                            const float* __restrict__ mW2, const float* __restrict__ mb2,
                            float* __restrict__ bias_tbl) {
    int p = blockIdx.x * blockDim.x + threadIdx.x;
    if (p >= NT * NT) return;
    int n = p >> 6, m = p & 63;
    float di = (float)((n >> 3) - (m >> 3));
    float dj = (float)((n & 7) - (m & 7));
    float r0 = copysignf(log1pf(fabsf(di)), di);
    float r1 = copysignf(log1pf(fabsf(dj)), dj);
    float acc[NH];
#pragma unroll
    for (int h = 0; h < NH; h++) acc[h] = mb2[h];
    for (int k = 0; k < MH; k++) {
        float hv = fmaxf(r0 * mW1[k] + r1 * mW1[MH + k] + mb1[k], 0.0f);
#pragma unroll
        for (int h = 0; h < NH; h++) acc[h] += hv * mW2[k * NH + h];
    }
#pragma unroll
    for (int h = 0; h < NH; h++) bias_tbl[h * (NT * NT) + p] = acc[h];
}

// ---------------- kernel 2: per-window attention ----------------
__launch_bounds__(384)
__global__ void attn_kernel(const float* __restrict__ x, const float* __restrict__ mask,
                            const float* __restrict__ Wqkv, const float* __restrict__ bqkv,
                            const float* __restrict__ Wproj, const float* __restrict__ bproj,
                            const float* __restrict__ tau, const float* __restrict__ bias_tbl,
                            float* __restrict__ out) {
    // tok[c][n]  (reused later as attention-output tokens, same layout)
    __shared__ __align__(16) float tok[CH * NT];            // 49152 B
    __shared__ __align__(16) float kl[NH * NT * KSTRIDE];   // 55296 B  khat[h][m][d]
    __shared__ __align__(16) float vl[NH * NT * KSTRIDE];   // 55296 B  v[h][m][d]

    const int b   = blockIdx.x;
    const int tid = threadIdx.x;
    const int l   = tid & 63;                                   // lane = token row
    const int w   = __builtin_amdgcn_readfirstlane(tid >> 6);   // wave = head (uniform)

    // ---- phase 0: stage x[b] -> tok (identical layout: c-major) ----
    const float4* xb   = (const float4*)(x + (size_t)b * (CH * NT));
    float4*       tok4 = (float4*)tok;
#pragma unroll
    for (int i = 0; i < (CH * NT / 4) / 384; i++) tok4[tid + i * 384] = xb[tid + i * 384];
    __syncthreads();

    // ---- phase 1: qkv GEMM ----
    // thread (w,l): q[l][w*32 .. w*32+31]  and  qkv-cols [192+64w .. 192+64w+63] (k or v strip)
    const int qoff  = w * HD;        // q column base (= head w)
    const int kvoff = CH + w * 64;   // k/v column base
    float qacc[HD];
    float kv[64];
#pragma unroll
    for (int d = 0; d < HD; d++) qacc[d] = bqkv[qoff + d];
#pragma unroll
    for (int j = 0; j < 64; j++) kv[j] = bqkv[kvoff + j];

    for (int c = 0; c < CH; c++) {
        float t = tok[c * NT + l];                 // conflict-free lds read
        const float* Wr = Wqkv + c * (3 * CH);     // wave-uniform addresses below
#pragma unroll
        for (int d = 0; d < HD; d++) qacc[d] = fmaf(t, Wr[qoff + d], qacc[d]);
#pragma unroll
        for (int j = 0; j < 64; j++) kv[j] = fmaf(t, Wr[kvoff + j], kv[j]);
    }

    // l2-normalize q in-register
    {
        float s2 = 0.f;
#pragma unroll
        for (int d = 0; d < HD; d++) s2 += qacc[d] * qacc[d];
        float qi = 1.0f / fmaxf(sqrtf(s2), 1e-12f);
#pragma unroll
        for (int d = 0; d < HD; d++) qacc[d] *= qi;
    }

    // waves 0..2 hold k-strips (heads 2w,2w+1) -> normalize + store; waves 3..5 hold v
    if (w < 3) {
        float n0 = 0.f, n1 = 0.f;
#pragma unroll
        for (int j = 0; j < 32; j++) n0 += kv[j] * kv[j];
#pragma unroll
        for (int j = 0; j < 32; j++) n1 += kv[32 + j] * kv[32 + j];
        float i0 = 1.0f / fmaxf(sqrtf(n0), 1e-12f);
        float i1 = 1.0f / fmaxf(sqrtf(n1), 1e-12f);
        float* kp0 = kl + (2 * w) * (NT * KSTRIDE) + l * KSTRIDE;
        float* kp1 = kl + (2 * w + 1) * (NT * KSTRIDE) + l * KSTRIDE;
#pragma unroll
        for (int j = 0; j < 8; j++) {
            float4 f;
            f.x = kv[4 * j + 0] * i0; f.y = kv[4 * j + 1] * i0;
            f.z = kv[4 * j + 2] * i0; f.w = kv[4 * j + 3] * i0;
            *(float4*)(kp0 + 4 * j) = f;
            float4 g;
            g.x = kv[32 + 4 * j + 0] * i1; g.y = kv[32 + 4 * j + 1] * i1;
            g.z = kv[32 + 4 * j + 2] * i1; g.w = kv[32 + 4 * j + 3] * i1;
            *(float4*)(kp1 + 4 * j) = g;
        }
    } else {
        float* vp0 = vl + (2 * (w - 3)) * (NT * KSTRIDE) + l * KSTRIDE;
        float* vp1 = vl + (2 * (w - 3) + 1) * (NT * KSTRIDE) + l * KSTRIDE;
#pragma unroll
        for (int j = 0; j < 8; j++) {
            float4 f;
            f.x = kv[4 * j + 0]; f.y = kv[4 * j + 1];
            f.z = kv[4 * j + 2]; f.w = kv[4 * j + 3];
            *(float4*)(vp0 + 4 * j) = f;
            float4 g;
            g.x = kv[32 + 4 * j + 0]; g.y = kv[32 + 4 * j + 1];
            g.z = kv[32 + 4 * j + 2]; g.w = kv[32 + 4 * j + 3];
            *(float4*)(vp1 + 4 * j) = g;
        }
    }
    __syncthreads();

    // ---- phase 2: logits + softmax + PV (thread (w,l) = head w, query row l) ----
    const int idx = b & 63;
    float s[NT];
    {
        const float4* br = (const float4*)(bias_tbl + w * (NT * NT) + l * NT);
        const float4* mr = (const float4*)(mask + idx * (NT * NT) + l * NT);
#pragma unroll
        for (int i = 0; i < 16; i++) {
            float4 bb = br[i], mm = mr[i];
            s[4 * i + 0] = bb.x + mm.x; s[4 * i + 1] = bb.y + mm.y;
            s[4 * i + 2] = bb.z + mm.z; s[4 * i + 3] = bb.w + mm.w;
        }
    }
    const float itau = 1.0f / fmaxf(tau[w], 0.01f);

#pragma unroll
    for (int m = 0; m < NT; m++) {
        const float4* kr = (const float4*)(kl + w * (NT * KSTRIDE) + m * KSTRIDE);
        float dot = 0.f;
#pragma unroll
        for (int j = 0; j < 8; j++) {
            float4 kk = kr[j];
            dot += qacc[4 * j + 0] * kk.x + qacc[4 * j + 1] * kk.y
                 + qacc[4 * j + 2] * kk.z + qacc[4 * j + 3] * kk.w;
        }
        s[m] = fmaf(dot, itau, s[m]);
    }

    // softmax over m (in-register)
    float mx = s[0];
#pragma unroll
    for (int m = 1; m < NT; m++) mx = fmaxf(mx, s[m]);
    float sum = 0.f;
#pragma unroll
    for (int m = 0; m < NT; m++) { s[m] = __expf(s[m] - mx); sum += s[m]; }
    const float isum = 1.0f / sum;

    // PV
    float o[HD];
#pragma unroll
    for (int d = 0; d < HD; d++) o[d] = 0.f;
#pragma unroll
    for (int m = 0; m < NT; m++) {
        const float4* vr = (const float4*)(vl + w * (NT * KSTRIDE) + m * KSTRIDE);
        float pm = s[m];
#pragma unroll
        for (int j = 0; j < 8; j++) {
            float4 vv = vr[j];
            o[4 * j + 0] = fmaf(pm, vv.x, o[4 * j + 0]);
            o[4 * j + 1] = fmaf(pm, vv.y, o[4 * j + 1]);
            o[4 * j + 2] = fmaf(pm, vv.z, o[4 * j + 2]);
            o[4 * j + 3] = fmaf(pm, vv.w, o[4 * j + 3]);
        }
    }

    // write attention output tokens into tok region: ot[c = w*32+d][n = l]
    // (tok is dead after phase 1; everyone is past the phase-1 barrier)
#pragma unroll
    for (int d = 0; d < HD; d++) tok[(qoff + d) * NT + l] = o[d] * isum;
    __syncthreads();

    // ---- phase 3: proj GEMM ----
    // thread (w,l): y[c][l] for c in [32w, 32w+32)
    float acc2[HD];
#pragma unroll
    for (int j = 0; j < HD; j++) acc2[j] = bproj[qoff + j];
    for (int c = 0; c < CH; c++) {
        float t = tok[c * NT + l];
        const float* Wr = Wproj + c * CH;
#pragma unroll
        for (int j = 0; j < HD; j++) acc2[j] = fmaf(t, Wr[qoff + j], acc2[j]);
    }
    float* ob = out + (size_t)b * (CH * NT);
#pragma unroll
    for (int j = 0; j < HD; j++) ob[(qoff + j) * NT + l] = acc2[j];
}

// ---------------- launcher ----------------
extern "C" void kernel_launch(void* const* d_in, const int* in_sizes, int n_in,
                              void* d_out, int out_size, void* d_ws, size_t ws_size,
                              hipStream_t stream) {
    const float* x     = (const float*)d_in[0];
    const float* mask  = (const float*)d_in[1];
    const float* Wqkv  = (const float*)d_in[2];
    const float* bqkv  = (const float*)d_in[3];
    const float* Wproj = (const float*)d_in[4];
    const float* bproj = (const float*)d_in[5];
    const float* mW1   = (const float*)d_in[6];
    const float* mb1   = (const float*)d_in[7];
    const float* mW2   = (const float*)d_in[8];
    const float* mb2   = (const float*)d_in[9];
    const float* tau   = (const float*)d_in[10];

    float* bias_tbl = (float*)d_ws;   // 6*64*64 floats = 96 KB

    bias_kernel<<<16, 256, 0, stream>>>(mW1, mb1, mW2, mb2, bias_tbl);
    attn_kernel<<<BWIN, 384, 0, stream>>>(x, mask, Wqkv, bqkv, Wproj, bproj, tau,
                                          bias_tbl, (float*)d_out);
}

// Round 2
// 536.037 us; speedup vs baseline: 6.8998x; 6.8998x over previous
//
#include <hip/hip_runtime.h>

typedef _Float16 f16;
typedef _Float16 f16x8 __attribute__((ext_vector_type(8)));
typedef float f32x4 __attribute__((ext_vector_type(4)));

#define NT 64
#define CH 192
#define NH 6
#define HD 32
#define MH 256
#define BWIN 4096

#define STOK 200   // tok/ao row stride (f16 elems): 400 B, quad-stride 25 (odd -> conflict-free b128)
#define SQK  40    // Qh/Kh row stride: 80 B, quad 5
#define SPV  72    // P / Vt row stride: 144 B, quad 9

// LDS layout (bytes)
#define OFF_P    0          // P: 6*64*72*2 = 55296 ; tok overlays: 64*200*2 = 25600
#define OFF_QH   55296      // Qh: 6*64*40*2 = 30720 ; ao overlays: 25600
#define OFF_KH   86016      // Kh: 30720
#define OFF_VT   116736     // Vt: 6*32*72*2 = 27648
#define SMEM_BYTES 144384

// ws layout (bytes)
#define WS_BIAS   0                       // fp32 bias_t[6][64][64] = 98304
#define WS_WTQ    98304                   // f16 Wtq[576][192]     = 221184
#define WS_WTP    319488                  // f16 Wtp[192][192]     = 73728
#define WS_MASKT  393216                  // fp32 mask_t[64][64][64] = 1048576

// ---------------- bias table (transposed: bias_t[h][m][n]) ----------------
__global__ void bias_kernel(const float* __restrict__ mW1, const float* __restrict__ mb1,
                            const float* __restrict__ mW2, const float* __restrict__ mb2,
                            float* __restrict__ bias_t) {
    int p = blockIdx.x * blockDim.x + threadIdx.x;
    if (p >= NT * NT) return;
    int n = p >> 6, m = p & 63;
    float di = (float)((n >> 3) - (m >> 3));
    float dj = (float)((n & 7) - (m & 7));
    float r0 = copysignf(log1pf(fabsf(di)), di);
    float r1 = copysignf(log1pf(fabsf(dj)), dj);
    float acc[NH];
#pragma unroll
    for (int h = 0; h < NH; h++) acc[h] = mb2[h];
    for (int k = 0; k < MH; k++) {
        float hv = fmaxf(r0 * mW1[k] + r1 * mW1[MH + k] + mb1[k], 0.0f);
#pragma unroll
        for (int h = 0; h < NH; h++) acc[h] += hv * mW2[k * NH + h];
    }
#pragma unroll
    for (int h = 0; h < NH; h++) bias_t[h * (NT * NT) + m * NT + n] = acc[h];
}

// ---------------- weight transpose + fp16 cast + mask transpose ----------------
__global__ void prep_kernel(const float* __restrict__ Wqkv, const float* __restrict__ Wproj,
                            const float* __restrict__ mask,
                            f16* __restrict__ Wtq, f16* __restrict__ Wtp,
                            float* __restrict__ mask_t) {
    int i = blockIdx.x * blockDim.x + threadIdx.x;
    if (i < 576 * 192) {
        int o = i / 192, c = i % 192;
        Wtq[i] = (f16)Wqkv[c * 576 + o];
    } else if (i < 576 * 192 + 192 * 192) {
        int j = i - 576 * 192;
        int o = j / 192, c = j % 192;
        Wtp[j] = (f16)Wproj[c * 192 + o];
    } else if (i < 576 * 192 + 192 * 192 + 64 * 64 * 64) {
        int j = i - (576 * 192 + 192 * 192);
        int im = j >> 12, m = (j >> 6) & 63, n = j & 63;
        mask_t[j] = mask[im * 4096 + n * 64 + m];
    }
}

// ---------------- main kernel: one block = one window, 6 waves = 6 heads ----------------
__launch_bounds__(384)
__global__ void attn_kernel(const float* __restrict__ x, const float* __restrict__ bqkv,
                            const float* __restrict__ bproj, const float* __restrict__ tau,
                            const f16* __restrict__ Wtq, const f16* __restrict__ Wtp,
                            const float* __restrict__ bias_t, const float* __restrict__ mask_t,
                            float* __restrict__ out) {
    __shared__ __align__(16) char smem[SMEM_BYTES];
    f16* tok = (f16*)(smem + OFF_P);    // [64][STOK]  (phase 0/1)
    f16* Pb  = (f16*)(smem + OFF_P);    // [6][64][SPV] (phase 2, overlays tok)
    f16* Qh  = (f16*)(smem + OFF_QH);   // [6][64][SQK]
    f16* ao  = (f16*)(smem + OFF_QH);   // [64][STOK]  (phase 2/3, overlays Qh)
    f16* Kh  = (f16*)(smem + OFF_KH);   // [6][64][SQK]
    f16* Vt  = (f16*)(smem + OFF_VT);   // [6][32][SPV]

    const int b   = blockIdx.x;
    const int tid = threadIdx.x;
    const int l   = tid & 63;
    const int w   = __builtin_amdgcn_readfirstlane(tid >> 6);
    const int c16 = l & 15;
    const int g4  = l >> 4;

    // ---- phase 0: stage x[b] (fp32 [c][n]) -> tok fp16 [n][c] ----
    {
        const float* xb = x + (size_t)b * (CH * NT);
#pragma unroll
        for (int it = 0; it < 32; it++) {
            int c = w * 32 + it;
            tok[l * STOK + c] = (f16)xb[c * NT + l];
        }
    }
    __syncthreads();

    // ---- phase 1: qkv GEMM.  D[n][col] = sum_c tok[n][c] * W[c][col] ----
    // A-frags (tokens) hoisted once for all 3 passes.
    f16x8 afrag[6][4];
#pragma unroll
    for (int ks = 0; ks < 6; ks++)
#pragma unroll
        for (int rt = 0; rt < 4; rt++)
            afrag[ks][rt] = *(const f16x8*)(tok + (16 * rt + c16) * STOK + ks * 32 + 8 * g4);

    const int role = w >> 1;        // 0=Q, 1=K, 2=V
    const int hb   = (w & 1) * 3;   // head base

#pragma unroll
    for (int p = 0; p < 3; p++) {
        const int head = hb + p;
        f32x4 acc[2][4] = {};
#pragma unroll
        for (int ks = 0; ks < 6; ks++) {
#pragma unroll
            for (int c2 = 0; c2 < 2; c2++) {
                const int ct = w * 6 + p * 2 + c2;
                f16x8 bf = *(const f16x8*)(Wtq + (size_t)(16 * ct + c16) * CH + ks * 32 + 8 * g4);
#pragma unroll
                for (int rt = 0; rt < 4; rt++)
                    acc[c2][rt] = __builtin_amdgcn_mfma_f32_16x16x32_f16(afrag[ks][rt], bf, acc[c2][rt], 0, 0, 0);
            }
        }
        // add qkv bias (per output column)
        float bb0 = bqkv[16 * (w * 6 + 2 * p) + c16];
        float bb1 = bqkv[16 * (w * 6 + 2 * p) + 16 + c16];
#pragma unroll
        for (int rt = 0; rt < 4; rt++)
#pragma unroll
            for (int r = 0; r < 4; r++) { acc[0][rt][r] += bb0; acc[1][rt][r] += bb1; }

        if (role < 2) {
            // l2-normalize each row over d=32 (both c2 halves), write Qhat/Khat fp16
            f16* dst = (role == 0 ? Qh : Kh) + head * (NT * SQK);
#pragma unroll
            for (int rt = 0; rt < 4; rt++)
#pragma unroll
                for (int r = 0; r < 4; r++) {
                    float ss = acc[0][rt][r] * acc[0][rt][r] + acc[1][rt][r] * acc[1][rt][r];
#pragma unroll
                    for (int off = 1; off < 16; off <<= 1) ss += __shfl_xor(ss, off);
                    float inv = 1.0f / fmaxf(sqrtf(ss), 1e-12f);
                    int n = 16 * rt + 4 * g4 + r;
                    dst[n * SQK + c16]      = (f16)(acc[0][rt][r] * inv);
                    dst[n * SQK + 16 + c16] = (f16)(acc[1][rt][r] * inv);
                }
        } else {
            // V: store transposed Vt[head][d][m]
            f16* dst = Vt + head * (HD * SPV);
#pragma unroll
            for (int rt = 0; rt < 4; rt++)
#pragma unroll
                for (int r = 0; r < 4; r++) {
                    int n = 16 * rt + 4 * g4 + r;
                    dst[c16 * SPV + n]        = (f16)acc[0][rt][r];
                    dst[(16 + c16) * SPV + n] = (f16)acc[1][rt][r];
                }
        }
    }
    __syncthreads();

    // ---- phase 2: attention, wave w = head w ----
    const float itau = 1.0f / fmaxf(tau[w], 0.01f);
    const int midx = b & 63;

    f32x4 sv[4][4];   // S tiles [rt][mt]
    {
        f16x8 aq[4], bk[4];
        const f16* qh = Qh + w * (NT * SQK);
        const f16* kh = Kh + w * (NT * SQK);
#pragma unroll
        for (int t = 0; t < 4; t++) {
            aq[t] = *(const f16x8*)(qh + (16 * t + c16) * SQK + 8 * g4);
            bk[t] = *(const f16x8*)(kh + (16 * t + c16) * SQK + 8 * g4);
        }
#pragma unroll
        for (int rt = 0; rt < 4; rt++)
#pragma unroll
            for (int mt = 0; mt < 4; mt++) {
                f32x4 z = {};
                sv[rt][mt] = __builtin_amdgcn_mfma_f32_16x16x32_f16(aq[rt], bk[mt], z, 0, 0, 0);
            }
    }
    // epilogue: scale + bias + mask (both pre-transposed -> float4 over rows)
    const float* bt = bias_t + w * (NT * NT);
    const float* mk = mask_t + midx * (NT * NT);
#pragma unroll
    for (int rt = 0; rt < 4; rt++)
#pragma unroll
        for (int mt = 0; mt < 4; mt++) {
            f32x4 bb = *(const f32x4*)(bt + (16 * mt + c16) * NT + 16 * rt + 4 * g4);
            f32x4 mm = *(const f32x4*)(mk + (16 * mt + c16) * NT + 16 * rt + 4 * g4);
#pragma unroll
            for (int r = 0; r < 4; r++)
                sv[rt][mt][r] = sv[rt][mt][r] * itau + bb[r] + mm[r];
        }

    // softmax over m (rows live in 16-lane groups)
    float risum[4][4];
#pragma unroll
    for (int rt = 0; rt < 4; rt++)
#pragma unroll
        for (int r = 0; r < 4; r++) {
            float m0 = fmaxf(fmaxf(sv[rt][0][r], sv[rt][1][r]), fmaxf(sv[rt][2][r], sv[rt][3][r]));
#pragma unroll
            for (int off = 1; off < 16; off <<= 1) m0 = fmaxf(m0, __shfl_xor(m0, off));
            float sum = 0.f;
#pragma unroll
            for (int mt = 0; mt < 4; mt++) {
                float pv = exp2f((sv[rt][mt][r] - m0) * 1.44269504f + 4.0f);  // scaled by 16, cancels in 1/sum
                sv[rt][mt][r] = pv;
                sum += pv;
            }
#pragma unroll
            for (int off = 1; off < 16; off <<= 1) sum += __shfl_xor(sum, off);
            risum[rt][r] = 1.0f / sum;
        }

    // write P (fp16) to own-head LDS region (overlays dead tok)
    f16* pw = Pb + w * (NT * SPV);
#pragma unroll
    for (int rt = 0; rt < 4; rt++)
#pragma unroll
        for (int mt = 0; mt < 4; mt++)
#pragma unroll
            for (int r = 0; r < 4; r++)
                pw[(16 * rt + 4 * g4 + r) * SPV + 16 * mt + c16] = (f16)sv[rt][mt][r];

    // barrier: orders own P write->read AND ensures all Qh/Kh reads done before ao writes
    __syncthreads();

    // PV: D[n][d] = sum_m P[n][m] * V[m][d]
    f32x4 av[4][2];
    {
        f16x8 pa[4][2], bv[2][2];
        const f16* vh = Vt + w * (HD * SPV);
#pragma unroll
        for (int rt = 0; rt < 4; rt++)
#pragma unroll
            for (int ms = 0; ms < 2; ms++)
                pa[rt][ms] = *(const f16x8*)(pw + (16 * rt + c16) * SPV + 32 * ms + 8 * g4);
#pragma unroll
        for (int dt = 0; dt < 2; dt++)
#pragma unroll
            for (int ms = 0; ms < 2; ms++)
                bv[dt][ms] = *(const f16x8*)(vh + (16 * dt + c16) * SPV + 32 * ms + 8 * g4);
#pragma unroll
        for (int rt = 0; rt < 4; rt++)
#pragma unroll
            for (int dt = 0; dt < 2; dt++) {
                f32x4 z = {};
                z = __builtin_amdgcn_mfma_f32_16x16x32_f16(pa[rt][0], bv[dt][0], z, 0, 0, 0);
                z = __builtin_amdgcn_mfma_f32_16x16x32_f16(pa[rt][1], bv[dt][1], z, 0, 0, 0);
                av[rt][dt] = z;
            }
    }
    // normalize + write ao fp16 [n][c'] (overlays dead Qh)
#pragma unroll
    for (int rt = 0; rt < 4; rt++)
#pragma unroll
        for (int dt = 0; dt < 2; dt++)
#pragma unroll
            for (int r = 0; r < 4; r++)
                ao[(16 * rt + 4 * g4 + r) * STOK + 32 * w + 16 * dt + c16] =
                    (f16)(av[rt][dt][r] * risum[rt][r]);

    __syncthreads();

    // ---- phase 3: proj GEMM. D[n][c] = sum_c' ao[n][c'] * Wp[c'][c]; wave w: c-tiles {2w, 2w+1} ----
    f32x4 acc2[2][4] = {};
#pragma unroll
    for (int ks = 0; ks < 6; ks++) {
        f16x8 af[4];
#pragma unroll
        for (int rt = 0; rt < 4; rt++)
            af[rt] = *(const f16x8*)(ao + (16 * rt + c16) * STOK + ks * 32 + 8 * g4);
#pragma unroll
        for (int c2 = 0; c2 < 2; c2++) {
            int ct = 2 * w + c2;
            f16x8 bw = *(const f16x8*)(Wtp + (size_t)(16 * ct + c16) * CH + ks * 32 + 8 * g4);
#pragma unroll
            for (int rt = 0; rt < 4; rt++)
                acc2[c2][rt] = __builtin_amdgcn_mfma_f32_16x16x32_f16(af[rt], bw, acc2[c2][rt], 0, 0, 0);
        }
    }
    // epilogue: +bproj, store float4 along n (coalesced 64B chunks)
    float* ob = out + (size_t)b * (CH * NT);
#pragma unroll
    for (int c2 = 0; c2 < 2; c2++) {
        int c = 16 * (2 * w + c2) + c16;
        float bp = bproj[c];
#pragma unroll
        for (int rt = 0; rt < 4; rt++) {
            f32x4 o4 = acc2[c2][rt];
            o4[0] += bp; o4[1] += bp; o4[2] += bp; o4[3] += bp;
            *(f32x4*)(ob + c * NT + 16 * rt + 4 * g4) = o4;
        }
    }
}

// ---------------- launcher ----------------
extern "C" void kernel_launch(void* const* d_in, const int* in_sizes, int n_in,
                              void* d_out, int out_size, void* d_ws, size_t ws_size,
                              hipStream_t stream) {
    const float* x     = (const float*)d_in[0];
    const float* mask  = (const float*)d_in[1];
    const float* Wqkv  = (const float*)d_in[2];
    const float* bqkv  = (const float*)d_in[3];
    const float* Wproj = (const float*)d_in[4];
    const float* bproj = (const float*)d_in[5];
    const float* mW1   = (const float*)d_in[6];
    const float* mb1   = (const float*)d_in[7];
    const float* mW2   = (const float*)d_in[8];
    const float* mb2   = (const float*)d_in[9];
    const float* tau   = (const float*)d_in[10];

    char* ws = (char*)d_ws;
    float* bias_t = (float*)(ws + WS_BIAS);
    f16*   Wtq    = (f16*)(ws + WS_WTQ);
    f16*   Wtp    = (f16*)(ws + WS_WTP);
    float* mask_t = (float*)(ws + WS_MASKT);

    bias_kernel<<<16, 256, 0, stream>>>(mW1, mb1, mW2, mb2, bias_t);
    int prep_n = 576 * 192 + 192 * 192 + 64 * 64 * 64;
    prep_kernel<<<(prep_n + 255) / 256, 256, 0, stream>>>(Wqkv, Wproj, mask, Wtq, Wtp, mask_t);
    attn_kernel<<<BWIN, 384, 0, stream>>>(x, bqkv, bproj, tau, Wtq, Wtp, bias_t, mask_t,
                                          (float*)d_out);
}

// Round 3
// 530.290 us; speedup vs baseline: 6.9746x; 1.0108x over previous
//
#include <hip/hip_runtime.h>

typedef _Float16 f16;
typedef _Float16 f16x2 __attribute__((ext_vector_type(2)));
typedef _Float16 f16x4 __attribute__((ext_vector_type(4)));
typedef _Float16 f16x8 __attribute__((ext_vector_type(8)));
typedef float f32x4 __attribute__((ext_vector_type(4)));

#define NT 64
#define CH 192
#define NH 6
#define HD 32
#define MH 256
#define BWIN 4096
#define LOG2E 1.44269504f

#define STOK 200   // tok/ao row stride (f16): 400 B, 16B-aligned rows
#define SQK  40    // Qhat/Khat row stride (f16): 80 B

// Single overlaid LDS region:
//   phase 0/1 : tok [64][STOK] f16              = 25600 B
//   phase 2   : qk  [6][2][64][SQK] f16         = 61440 B   (h: 0=Qhat,1=Khat)
//   phase 2/3 : ao  [64][STOK] f16              = 25600 B
#define SMEM_BYTES 61440

#if __has_builtin(__builtin_amdgcn_mfma_f32_16x16x16f16)
#define MFMA16(a, b, c) __builtin_amdgcn_mfma_f32_16x16x16f16(a, b, c, 0, 0, 0)
#elif __has_builtin(__builtin_amdgcn_mfma_f32_16x16x16_f16)
#define MFMA16(a, b, c) __builtin_amdgcn_mfma_f32_16x16x16_f16(a, b, c, 0, 0, 0)
#else
static __device__ inline f32x4 mfma16_asm(f16x4 a, f16x4 b, f32x4 c) {
    f32x4 d;
    asm volatile("v_mfma_f32_16x16x16_f16 %0, %1, %2, %3"
                 : "=v"(d) : "v"(a), "v"(b), "v"(c));
    return d;
}
#define MFMA16(a, b, c) mfma16_asm(a, b, c)
#endif
#define MFMA32(a, b, c) __builtin_amdgcn_mfma_f32_16x16x32_f16(a, b, c, 0, 0, 0)

// ---------------- bias table (natural layout bias[h][n][m]) ----------------
__global__ void bias_kernel(const float* __restrict__ mW1, const float* __restrict__ mb1,
                            const float* __restrict__ mW2, const float* __restrict__ mb2,
                            float* __restrict__ bias_tbl) {
    int p = blockIdx.x * blockDim.x + threadIdx.x;
    if (p >= NT * NT) return;
    int n = p >> 6, m = p & 63;
    float di = (float)((n >> 3) - (m >> 3));
    float dj = (float)((n & 7) - (m & 7));
    float r0 = copysignf(log1pf(fabsf(di)), di);
    float r1 = copysignf(log1pf(fabsf(dj)), dj);
    float acc[NH];
#pragma unroll
    for (int h = 0; h < NH; h++) acc[h] = mb2[h];
    for (int k = 0; k < MH; k++) {
        float hv = fmaxf(r0 * mW1[k] + r1 * mW1[MH + k] + mb1[k], 0.0f);
#pragma unroll
        for (int h = 0; h < NH; h++) acc[h] += hv * mW2[k * NH + h];
    }
#pragma unroll
    for (int h = 0; h < NH; h++) bias_tbl[h * (NT * NT) + p] = acc[h];
}

// ---------------- weight transpose + fp16 cast ----------------
__global__ void prep_kernel(const float* __restrict__ Wqkv, const float* __restrict__ Wproj,
                            f16* __restrict__ Wtq, f16* __restrict__ Wtp) {
    int i = blockIdx.x * blockDim.x + threadIdx.x;
    if (i < 576 * 192) {
        int o = i / 192, c = i % 192;
        Wtq[i] = (f16)Wqkv[c * 576 + o];
    } else if (i < 576 * 192 + 192 * 192) {
        int j = i - 576 * 192;
        int o = j / 192, c = j % 192;
        Wtp[j] = (f16)Wproj[c * 192 + o];
    }
}

// ---------------- combined (mask + bias) * log2e table ----------------
// comb[im][h][n][m], im<64, h<6
__global__ void comb_kernel(const float* __restrict__ mask, const float* __restrict__ bias_tbl,
                            float* __restrict__ comb) {
    int j = blockIdx.x * blockDim.x + threadIdx.x;
    if (j >= 64 * NH * NT * NT) return;
    int im = j / (NH * NT * NT);
    int rem = j % (NH * NT * NT);
    int h = rem >> 12;
    int p = rem & 4095;
    comb[j] = (mask[im * 4096 + p] + bias_tbl[h * 4096 + p]) * LOG2E;
}

// ---------------- main kernel: 1 block = 1 window, wave w = head w ----------------
__launch_bounds__(384, 3)
__global__ void attn_kernel(const float* __restrict__ x, const float* __restrict__ bqkv,
                            const float* __restrict__ bproj, const float* __restrict__ tau,
                            const f16* __restrict__ Wtq, const f16* __restrict__ Wtp,
                            const float* __restrict__ comb, float* __restrict__ out) {
    __shared__ __align__(16) char smem[SMEM_BYTES];
    f16* tok = (f16*)smem;   // [64][STOK]
    f16* qk  = (f16*)smem;   // [6][2][64][SQK]
    f16* ao  = (f16*)smem;   // [64][STOK]

    const int b   = blockIdx.x;
    const int tid = threadIdx.x;
    const int l   = tid & 63;
    const int w   = __builtin_amdgcn_readfirstlane(tid >> 6);
    const int c16 = l & 15;
    const int g4  = l >> 4;

    // ---- phase 0: stage x[b] (fp32 [c][n]) -> tok f16 [n][c] ----
    {
        const float* xb = x + (size_t)b * (CH * NT);
#pragma unroll
        for (int it = 0; it < 16; it++) {
            int c = w * 32 + 2 * it;
            f16x2 p;
            p[0] = (f16)xb[c * NT + l];
            p[1] = (f16)xb[(c + 1) * NT + l];
            *(f16x2*)(tok + l * STOK + c) = p;
        }
    }
    __syncthreads();

    // ---- phase 1: qkv GEMM, wave w computes head w's Q,K,V ----
    // acc[q6][rt]: q6 = op*2+c2 (op 0=Q,1=K,2=V), D[n][16*ct+c16], n = 16rt+4g4+r
    f32x4 acc[6][4] = {};
    for (int ks = 0; ks < 6; ks++) {
        f16x8 af[4];
#pragma unroll
        for (int rt = 0; rt < 4; rt++)
            af[rt] = *(const f16x8*)(tok + (16 * rt + c16) * STOK + ks * 32 + 8 * g4);
#pragma unroll
        for (int q6 = 0; q6 < 6; q6++) {
            const int ct = (q6 >> 1) * 12 + 2 * w + (q6 & 1);
            f16x8 bf = *(const f16x8*)(Wtq + (size_t)(16 * ct + c16) * CH + ks * 32 + 8 * g4);
#pragma unroll
            for (int rt = 0; rt < 4; rt++)
                acc[q6][rt] = MFMA32(af[rt], bf, acc[q6][rt]);
        }
    }
    // add qkv bias (per output column)
#pragma unroll
    for (int q6 = 0; q6 < 6; q6++) {
        const int ct = (q6 >> 1) * 12 + 2 * w + (q6 & 1);
        float bb = bqkv[16 * ct + c16];
#pragma unroll
        for (int rt = 0; rt < 4; rt++)
#pragma unroll
            for (int r = 0; r < 4; r++) acc[q6][rt][r] += bb;
    }

    __syncthreads();   // all tok reads done -> qk may overlay

    // ---- normalize Q,K rows; write Qhat/Khat (per-wave private region) ----
    {
        f16* qh = qk + (w * 2 + 0) * (NT * SQK);
        f16* kh = qk + (w * 2 + 1) * (NT * SQK);
#pragma unroll
        for (int rt = 0; rt < 4; rt++)
#pragma unroll
            for (int r = 0; r < 4; r++) {
                int n = 16 * rt + 4 * g4 + r;
                float ssq = acc[0][rt][r] * acc[0][rt][r] + acc[1][rt][r] * acc[1][rt][r];
                float ssk = acc[2][rt][r] * acc[2][rt][r] + acc[3][rt][r] * acc[3][rt][r];
#pragma unroll
                for (int off = 1; off < 16; off <<= 1) {
                    ssq += __shfl_xor(ssq, off);
                    ssk += __shfl_xor(ssk, off);
                }
                float iq = 1.0f / fmaxf(sqrtf(ssq), 1e-12f);
                float ik = 1.0f / fmaxf(sqrtf(ssk), 1e-12f);
                qh[n * SQK + c16]      = (f16)(acc[0][rt][r] * iq);
                qh[n * SQK + 16 + c16] = (f16)(acc[1][rt][r] * iq);
                kh[n * SQK + c16]      = (f16)(acc[2][rt][r] * ik);
                kh[n * SQK + 16 + c16] = (f16)(acc[3][rt][r] * ik);
            }
    }

    // V -> f16 PV b-frags, directly from registers (layout matches exactly)
    f16x4 vb[2][4];   // [dt][mk]
#pragma unroll
    for (int dt = 0; dt < 2; dt++)
#pragma unroll
        for (int mk = 0; mk < 4; mk++) {
            f16x4 h;
#pragma unroll
            for (int r = 0; r < 4; r++) h[r] = (f16)acc[4 + dt][mk][r];
            vb[dt][mk] = h;
        }

    // ---- phase 2: S^T = Khat · Qhat^T  (lane=n, regs=m: PV A-frag layout) ----
    f32x4 sv[4][4];   // [mt][nt]
    {
        const f16* qh = qk + (w * 2 + 0) * (NT * SQK);
        const f16* kh = qk + (w * 2 + 1) * (NT * SQK);
        f16x8 ak[4], aq[4];
#pragma unroll
        for (int t = 0; t < 4; t++) {
            ak[t] = *(const f16x8*)(kh + (16 * t + c16) * SQK + 8 * g4);
            aq[t] = *(const f16x8*)(qh + (16 * t + c16) * SQK + 8 * g4);
        }
#pragma unroll
        for (int mt = 0; mt < 4; mt++)
#pragma unroll
            for (int nt = 0; nt < 4; nt++) {
                f32x4 z = {};
                sv[mt][nt] = MFMA32(ak[mt], aq[nt], z);
            }
    }

    // epilogue: sv*itau*log2e + comb   (comb pre-scaled by log2e)
    {
        const float itau_l2 = LOG2E / fmaxf(tau[w], 0.01f);
        const float* cb = comb + ((size_t)((b & 63) * NH + w)) * (NT * NT);
#pragma unroll
        for (int mt = 0; mt < 4; mt++)
#pragma unroll
            for (int nt = 0; nt < 4; nt++) {
                f32x4 cc = *(const f32x4*)(cb + (16 * nt + c16) * NT + 16 * mt + 4 * g4);
#pragma unroll
                for (int r = 0; r < 4; r++)
                    sv[mt][nt][r] = sv[mt][nt][r] * itau_l2 + cc[r];
            }
    }

    // softmax over m (per-lane 16 values + 2 cross-g4 shuffles), scale by 1/sum in place
#pragma unroll
    for (int nt = 0; nt < 4; nt++) {
        float mx = sv[0][nt][0];
#pragma unroll
        for (int mt = 0; mt < 4; mt++)
#pragma unroll
            for (int r = 0; r < 4; r++) mx = fmaxf(mx, sv[mt][nt][r]);
        mx = fmaxf(mx, __shfl_xor(mx, 16));
        mx = fmaxf(mx, __shfl_xor(mx, 32));
        float sum = 0.f;
#pragma unroll
        for (int mt = 0; mt < 4; mt++)
#pragma unroll
            for (int r = 0; r < 4; r++) {
                float p = exp2f(sv[mt][nt][r] - mx);
                sv[mt][nt][r] = p;
                sum += p;
            }
        sum += __shfl_xor(sum, 16);
        sum += __shfl_xor(sum, 32);
        float ris = 1.0f / sum;
#pragma unroll
        for (int mt = 0; mt < 4; mt++)
#pragma unroll
            for (int r = 0; r < 4; r++) sv[mt][nt][r] *= ris;
    }

    // P -> f16 PV a-frags (lane-local pack, layout matches exactly)
    f16x4 pa[4][4];   // [mk][nt]
#pragma unroll
    for (int mk = 0; mk < 4; mk++)
#pragma unroll
        for (int nt = 0; nt < 4; nt++) {
            f16x4 h;
#pragma unroll
            for (int r = 0; r < 4; r++) h[r] = (f16)sv[mk][nt][r];
            pa[mk][nt] = h;
        }

    // PV: out[n][d] += P[n][m] V[m][d], all operands in registers
    f32x4 av[4][2] = {};   // [nt][dt]
#pragma unroll
    for (int mk = 0; mk < 4; mk++)
#pragma unroll
        for (int nt = 0; nt < 4; nt++)
#pragma unroll
            for (int dt = 0; dt < 2; dt++)
                av[nt][dt] = MFMA16(pa[mk][nt], vb[dt][mk], av[nt][dt]);

    __syncthreads();   // all Qhat/Khat reads done -> ao may overlay

    // write attention-output tokens ao[n][c' = 32w+16dt+c16]
#pragma unroll
    for (int nt = 0; nt < 4; nt++)
#pragma unroll
        for (int dt = 0; dt < 2; dt++)
#pragma unroll
            for (int r = 0; r < 4; r++)
                ao[(16 * nt + 4 * g4 + r) * STOK + 32 * w + 16 * dt + c16] = (f16)av[nt][dt][r];
    __syncthreads();

    // ---- phase 3: proj GEMM, wave w -> output c-tiles {2w, 2w+1} ----
    f32x4 acc2[2][4] = {};
    for (int ks = 0; ks < 6; ks++) {
        f16x8 af[4];
#pragma unroll
        for (int rt = 0; rt < 4; rt++)
            af[rt] = *(const f16x8*)(ao + (16 * rt + c16) * STOK + ks * 32 + 8 * g4);
#pragma unroll
        for (int c2 = 0; c2 < 2; c2++) {
            int ct = 2 * w + c2;
            f16x8 bw = *(const f16x8*)(Wtp + (size_t)(16 * ct + c16) * CH + ks * 32 + 8 * g4);
#pragma unroll
            for (int rt = 0; rt < 4; rt++)
                acc2[c2][rt] = MFMA32(af[rt], bw, acc2[c2][rt]);
        }
    }
    // epilogue: +bproj, store float4 along n (coalesced 64B chunks)
    float* ob = out + (size_t)b * (CH * NT);
#pragma unroll
    for (int c2 = 0; c2 < 2; c2++) {
        int c = 16 * (2 * w + c2) + c16;
        float bp = bproj[c];
#pragma unroll
        for (int rt = 0; rt < 4; rt++) {
            f32x4 o4 = acc2[c2][rt];
            o4[0] += bp; o4[1] += bp; o4[2] += bp; o4[3] += bp;
            *(f32x4*)(ob + c * NT + 16 * rt + 4 * g4) = o4;
        }
    }
}

// ---------------- launcher ----------------
#define WS_BIAS 0
#define WS_WTQ  98304
#define WS_WTP  319488
#define WS_COMB 393216

extern "C" void kernel_launch(void* const* d_in, const int* in_sizes, int n_in,
                              void* d_out, int out_size, void* d_ws, size_t ws_size,
                              hipStream_t stream) {
    const float* x     = (const float*)d_in[0];
    const float* mask  = (const float*)d_in[1];
    const float* Wqkv  = (const float*)d_in[2];
    const float* bqkv  = (const float*)d_in[3];
    const float* Wproj = (const float*)d_in[4];
    const float* bproj = (const float*)d_in[5];
    const float* mW1   = (const float*)d_in[6];
    const float* mb1   = (const float*)d_in[7];
    const float* mW2   = (const float*)d_in[8];
    const float* mb2   = (const float*)d_in[9];
    const float* tau   = (const float*)d_in[10];

    char* ws = (char*)d_ws;
    float* bias_tbl = (float*)(ws + WS_BIAS);
    f16*   Wtq      = (f16*)(ws + WS_WTQ);
    f16*   Wtp      = (f16*)(ws + WS_WTP);
    float* comb     = (float*)(ws + WS_COMB);

    bias_kernel<<<16, 256, 0, stream>>>(mW1, mb1, mW2, mb2, bias_tbl);
    int prep_n = 576 * 192 + 192 * 192;
    prep_kernel<<<(prep_n + 255) / 256, 256, 0, stream>>>(Wqkv, Wproj, Wtq, Wtp);
    int comb_n = 64 * NH * NT * NT;
    comb_kernel<<<(comb_n + 255) / 256, 256, 0, stream>>>(mask, bias_tbl, comb);
    attn_kernel<<<BWIN, 384, 0, stream>>>(x, bqkv, bproj, tau, Wtq, Wtp, comb,
                                          (float*)d_out);
}